// Round 4
// baseline (166.752 us; speedup 1.0000x reference)
//
#include <hip/hip_runtime.h>

#define NROWS 4096
#define NCOLS 4096
#define TAU 0.95f
#define MARGIN 1.0f

// One WAVE per row; lane owns 64 contiguous elements. Labels (0/1) are packed
// into a 64-bit mask per lane, so the row cumsum needs only one wave-level
// shfl scan of popcounts -- NO LDS, NO barriers (R3 evidence: blocks were
// MLP-starved: ~1.8KB/CU in flight -> 1.6 TB/s; barriers+scan left memory
// idle). Y streams as a 16x float4 burst (16KB in flight per wave).
__global__ __launch_bounds__(256, 4) void attncut_kernel(
    const float* __restrict__ cut_y, const int* __restrict__ cut_label,
    float* __restrict__ partials) {
  const int wid = threadIdx.x >> 6;
  const int lane = threadIdx.x & 63;
  const int row = blockIdx.x * 4 + wid;

  const int* lbase = cut_label + (size_t)row * NCOLS + lane * 64;
  const float* ybase = cut_y + (size_t)row * NCOLS + lane * 64;
  const int4* Lp = (const int4*)lbase;
  const float4* Yp = (const float4*)ybase;

  // ---- Phase 1: label mask (issue all 16 int4 loads as one burst) ----
#define LDL(K) const int4 l##K = Lp[K];
  LDL(0) LDL(1) LDL(2) LDL(3) LDL(4) LDL(5) LDL(6) LDL(7)
  LDL(8) LDL(9) LDL(10) LDL(11) LDL(12) LDL(13) LDL(14) LDL(15)
#undef LDL

  unsigned int mlo = 0u, mhi = 0u;
#define PACKLO(K)                                                          \
  mlo |= ((unsigned)l##K.x | ((unsigned)l##K.y << 1) |                     \
          ((unsigned)l##K.z << 2) | ((unsigned)l##K.w << 3))               \
         << (4 * (K));
#define PACKHI(K)                                                          \
  mhi |= ((unsigned)l##K.x | ((unsigned)l##K.y << 1) |                     \
          ((unsigned)l##K.z << 2) | ((unsigned)l##K.w << 3))               \
         << (4 * ((K)-8));
  PACKLO(0) PACKLO(1) PACKLO(2) PACKLO(3)
  PACKLO(4) PACKLO(5) PACKLO(6) PACKLO(7)
  PACKHI(8) PACKHI(9) PACKHI(10) PACKHI(11)
  PACKHI(12) PACKHI(13) PACKHI(14) PACKHI(15)
#undef PACKLO
#undef PACKHI

  const int cnt = __popc(mlo) + __popc(mhi);

  // Wave-inclusive scan of per-lane counts (64 lanes, shfl only).
  int x = cnt;
#pragma unroll
  for (int off = 1; off < 64; off <<= 1) {
    int v = __shfl_up(x, off, 64);
    if (lane >= off) x += v;
  }
  const int Ttot = __shfl(x, 63, 64);  // row total, wave-uniform
  int c = x - cnt;                     // exclusive prefix for this lane

  // ---- Phase 2: stream Y (issue all 16 float4 loads as one burst) ----
#define LDY(K) const float4 y##K = Yp[K];
  LDY(0) LDY(1) LDY(2) LDY(3) LDY(4) LDY(5) LDY(6) LDY(7)
  LDY(8) LDY(9) LDY(10) LDY(11) LDY(12) LDY(13) LDY(14) LDY(15)
#undef LDY

  const float Tf = (float)Ttot;
  const float kbase = (float)(lane * 64);
  float norm_acc = 0.f, log_acc = 0.f;

#define ELEM(YV, J)                                                        \
  {                                                                        \
    const unsigned bit =                                                   \
        (((J) < 32) ? (mlo >> (J)) : (mhi >> ((J)-32))) & 1u;              \
    c += (int)bit;                                                         \
    float r = __fdividef(2.0f * (float)c, kbase + (float)((J) + 1) + Tf);  \
    r = (c > 0) ? r : 0.0f;                                                \
    norm_acc += __expf(r * (1.0f / TAU));                                  \
    log_acc += __logf(YV);                                                 \
  }
#define ELEM4(K)                                                           \
  ELEM(y##K.x, 4 * (K) + 0)                                                \
  ELEM(y##K.y, 4 * (K) + 1)                                                \
  ELEM(y##K.z, 4 * (K) + 2)                                                \
  ELEM(y##K.w, 4 * (K) + 3)
  ELEM4(0) ELEM4(1) ELEM4(2) ELEM4(3)
  ELEM4(4) ELEM4(5) ELEM4(6) ELEM4(7)
  ELEM4(8) ELEM4(9) ELEM4(10) ELEM4(11)
  ELEM4(12) ELEM4(13) ELEM4(14) ELEM4(15)
#undef ELEM4
#undef ELEM

  // Wave reduction (no LDS).
#pragma unroll
  for (int off = 32; off > 0; off >>= 1) {
    norm_acc += __shfl_down(norm_acc, off, 64);
    log_acc += __shfl_down(log_acc, off, 64);
  }
  if (lane == 0) partials[row] = -log_acc / (norm_acc * (float)NROWS);
}

// Single block: sum the 4096 per-row partials + rerank hinge loss.
__global__ __launch_bounds__(256) void finish_kernel(
    const float* __restrict__ partials, const float* __restrict__ rerank_y,
    float* __restrict__ out) {
  const int t = threadIdx.x;
  const int lane = t & 63, wid = t >> 6;

  float acc = 0.f;
  const float4* p4 = (const float4*)partials;  // 4096 floats = 1024 float4
#pragma unroll
  for (int i = 0; i < 4; ++i) {
    float4 v = p4[t + 256 * i];
    acc += (v.x + v.y) + (v.z + v.w);
  }

  float racc = 0.f;
  const float4* y4 = (const float4*)rerank_y;  // 8192 floats; float4 = 2 pairs
#pragma unroll
  for (int i = 0; i < 8; ++i) {
    float4 v = y4[t + 256 * i];
    racc += fmaxf(0.f, MARGIN - (v.x - v.y));
    racc += fmaxf(0.f, MARGIN - (v.z - v.w));
  }
  acc += racc * (1.0f / 4096.0f);

#pragma unroll
  for (int off = 32; off > 0; off >>= 1) acc += __shfl_down(acc, off, 64);
  __shared__ float ws[4];
  if (lane == 0) ws[wid] = acc;
  __syncthreads();
  if (t == 0) out[0] = (ws[0] + ws[1]) + (ws[2] + ws[3]);
}

extern "C" void kernel_launch(void* const* d_in, const int* in_sizes, int n_in,
                              void* d_out, int out_size, void* d_ws, size_t ws_size,
                              hipStream_t stream) {
  const float* rerank_y = (const float*)d_in[0];   // (8192, 1) f32
  const float* cut_y = (const float*)d_in[1];      // (4096, 4096, 1) f32
  // d_in[2] = rerank_label, unused by the reference loss
  const int* cut_label = (const int*)d_in[3];      // (4096, 4096) i32
  float* out = (float*)d_out;                      // scalar f32
  float* partials = (float*)d_ws;                  // 4096 f32 (16 KB scratch)

  attncut_kernel<<<NROWS / 4, 256, 0, stream>>>(cut_y, cut_label, partials);
  finish_kernel<<<1, 256, 0, stream>>>(partials, rerank_y, out);
}

// Round 5
// 154.857 us; speedup vs baseline: 1.0768x; 1.0768x over previous
//
#include <hip/hip_runtime.h>

#define NROWS 4096
#define NCOLS 4096
#define TAU 0.95f
#define MARGIN 1.0f

// Fused heterogeneous-grid kernel. The two per-row reductions are separable:
//   logsum_b = sum_s log(cut_y[b,s])        -- needs ONLY cut_y, zero deps
//   norm_b   = sum_s exp(r[b,s]/tau)        -- needs ONLY cut_label (scan)
// Blocks [0,4096): pure streaming logsum (no scan/barrier -> saturates HBM).
// Blocks [4096,8192): label scan + exp (barrier stalls hidden by co-resident
// streaming blocks). R4 post-mortem: single mega-burst per wave fails (compiler
// clamps VGPRs, 36 regs, 2.3 TB/s); heterogeneous grid keeps memory busy via
// TLP instead of per-wave MLP.
__global__ __launch_bounds__(256) void fused_kernel(
    const float* __restrict__ cut_y, const int* __restrict__ cut_label,
    float* __restrict__ norm_out, float* __restrict__ logsum_out) {
  const int t = threadIdx.x;
  const int lane = t & 63;
  const int wid = t >> 6;
  __shared__ float red[4];
  __shared__ int wsum[4];

  if (blockIdx.x < NROWS) {
    // ---------- logsum pass: row = blockIdx.x ----------
    const int row = blockIdx.x;
    const float4* Yp = (const float4*)(cut_y + (size_t)row * NCOLS);
    // Fully coalesced: lane-contiguous float4, 4 independent 4KB wave-loads.
    const float4 a0 = Yp[t];
    const float4 a1 = Yp[t + 256];
    const float4 a2 = Yp[t + 512];
    const float4 a3 = Yp[t + 768];
    float s = __logf(a0.x) + __logf(a0.y) + __logf(a0.z) + __logf(a0.w) +
              __logf(a1.x) + __logf(a1.y) + __logf(a1.z) + __logf(a1.w) +
              __logf(a2.x) + __logf(a2.y) + __logf(a2.z) + __logf(a2.w) +
              __logf(a3.x) + __logf(a3.y) + __logf(a3.z) + __logf(a3.w);
#pragma unroll
    for (int off = 32; off > 0; off >>= 1) s += __shfl_down(s, off, 64);
    if (lane == 0) red[wid] = s;
    __syncthreads();
    if (t == 0) logsum_out[row] = (red[0] + red[1]) + (red[2] + red[3]);
  } else {
    // ---------- norm pass: row = blockIdx.x - NROWS ----------
    const int row = blockIdx.x - NROWS;
    const int4* Lp = (const int4*)(cut_label + (size_t)row * NCOLS) + t * 4;
    const int4 L0 = Lp[0], L1 = Lp[1], L2 = Lp[2], L3 = Lp[3];

    const int lsum = L0.x + L0.y + L0.z + L0.w + L1.x + L1.y + L1.z + L1.w +
                     L2.x + L2.y + L2.z + L2.w + L3.x + L3.y + L3.z + L3.w;

    // Wave-inclusive scan of per-thread label sums.
    int x = lsum;
#pragma unroll
    for (int off = 1; off < 64; off <<= 1) {
      int v = __shfl_up(x, off, 64);
      if (lane >= off) x += v;
    }
    if (lane == 63) wsum[wid] = x;
    __syncthreads();
    int prev = 0;
#pragma unroll
    for (int w = 0; w < 4; ++w)
      if (w < wid) prev += wsum[w];
    const int Ttot = wsum[0] + wsum[1] + wsum[2] + wsum[3];
    int c = prev + x - lsum;  // exclusive prefix for this thread's 16-chunk

    const float Tf = (float)Ttot;
    const float kbase = (float)(t * 16);
    float norm_acc = 0.f;

#define STEP(LAB, J)                                                     \
  {                                                                      \
    c += (LAB);                                                          \
    float r = __fdividef(2.0f * (float)c, kbase + (float)((J) + 1) + Tf);\
    r = (c > 0) ? r : 0.0f;                                              \
    norm_acc += __expf(r * (1.0f / TAU));                                \
  }
    STEP(L0.x, 0)  STEP(L0.y, 1)  STEP(L0.z, 2)  STEP(L0.w, 3)
    STEP(L1.x, 4)  STEP(L1.y, 5)  STEP(L1.z, 6)  STEP(L1.w, 7)
    STEP(L2.x, 8)  STEP(L2.y, 9)  STEP(L2.z, 10) STEP(L2.w, 11)
    STEP(L3.x, 12) STEP(L3.y, 13) STEP(L3.z, 14) STEP(L3.w, 15)
#undef STEP

#pragma unroll
    for (int off = 32; off > 0; off >>= 1)
      norm_acc += __shfl_down(norm_acc, off, 64);
    if (lane == 0) red[wid] = norm_acc;
    __syncthreads();
    if (t == 0) norm_out[row] = (red[0] + red[1]) + (red[2] + red[3]);
  }
}

// Single block: combine per-row (logsum, norm) + rerank hinge loss.
__global__ __launch_bounds__(256) void finish_kernel(
    const float* __restrict__ norms, const float* __restrict__ logsums,
    const float* __restrict__ rerank_y, float* __restrict__ out) {
  const int t = threadIdx.x;
  const int lane = t & 63, wid = t >> 6;

  float acc = 0.f;
  const float4* n4 = (const float4*)norms;    // 4096 floats = 1024 float4
  const float4* l4 = (const float4*)logsums;
#pragma unroll
  for (int i = 0; i < 4; ++i) {
    const float4 n = n4[t + 256 * i];
    const float4 l = l4[t + 256 * i];
    acc += __fdividef(l.x, n.x) + __fdividef(l.y, n.y) +
           __fdividef(l.z, n.z) + __fdividef(l.w, n.w);
  }
  acc *= -(1.0f / (float)NROWS);

  float racc = 0.f;
  const float4* y4 = (const float4*)rerank_y;  // 8192 floats; float4 = 2 pairs
#pragma unroll
  for (int i = 0; i < 8; ++i) {
    const float4 v = y4[t + 256 * i];
    racc += fmaxf(0.f, MARGIN - (v.x - v.y));
    racc += fmaxf(0.f, MARGIN - (v.z - v.w));
  }
  acc += racc * (1.0f / 4096.0f);

#pragma unroll
  for (int off = 32; off > 0; off >>= 1) acc += __shfl_down(acc, off, 64);
  __shared__ float ws[4];
  if (lane == 0) ws[wid] = acc;
  __syncthreads();
  if (t == 0) out[0] = (ws[0] + ws[1]) + (ws[2] + ws[3]);
}

extern "C" void kernel_launch(void* const* d_in, const int* in_sizes, int n_in,
                              void* d_out, int out_size, void* d_ws, size_t ws_size,
                              hipStream_t stream) {
  const float* rerank_y = (const float*)d_in[0];   // (8192, 1) f32
  const float* cut_y = (const float*)d_in[1];      // (4096, 4096, 1) f32
  // d_in[2] = rerank_label, unused by the reference loss
  const int* cut_label = (const int*)d_in[3];      // (4096, 4096) i32
  float* out = (float*)d_out;                      // scalar f32
  float* norms = (float*)d_ws;                     // 4096 f32
  float* logsums = (float*)d_ws + NROWS;           // 4096 f32

  fused_kernel<<<2 * NROWS, 256, 0, stream>>>(cut_y, cut_label, norms, logsums);
  finish_kernel<<<1, 256, 0, stream>>>(norms, logsums, rerank_y, out);
}